// Round 2
// baseline (320.963 us; speedup 1.0000x reference)
//
#include <hip/hip_runtime.h>
#include <hip/hip_bf16.h>
#include <hip/hip_fp16.h>

#define L_LEN 16384
#define NB 64
#define NCHUNK 32
#define CHUNK 512

typedef short bf16x8 __attribute__((ext_vector_type(8)));
typedef float f32x4 __attribute__((ext_vector_type(4)));
typedef unsigned int u32x4 __attribute__((ext_vector_type(4)));

__device__ __forceinline__ unsigned short f2bf(float f) {
    unsigned u = __float_as_uint(f);
    return (unsigned short)((u + 0x7FFFu + ((u >> 16) & 1u)) >> 16);  // RNE
}

// round-half-up float->bf16 (bits), cheap: (u + 0x8000) >> 16
__device__ __forceinline__ unsigned rhu_lo(float f) {
    return (__float_as_uint(f) + 0x8000u) >> 16;
}
__device__ __forceinline__ unsigned rhu_hi(float f) {
    return (__float_as_uint(f) + 0x8000u) & 0xFFFF0000u;
}

// tanh-form GELU via sigmoid: x / (1 + exp2(x*(c1 + c2*x^2)))
__device__ __forceinline__ float gelu_f(float x) {
    float x2 = x * x;
    float f  = x * fmaf(-0.1029437f, x2, -2.30220789f);
    float e  = __builtin_amdgcn_exp2f(f);
    return x * __builtin_amdgcn_rcpf(1.0f + e);
}

// K0: W2 [128][128] f32 -> W2T [n][k] bf16 (transposed) in ws
__global__ __launch_bounds__(256) void k0_prep(const float* __restrict__ W2,
                                               unsigned short* __restrict__ w2t) {
    int i = blockIdx.x * 256 + threadIdx.x;   // 0..16383
    int n = i >> 7, k = i & 127;
    w2t[i] = f2bf(W2[k * 128 + n]);
}

// K1: fused dx -> gelu(dx@W1+b1) in-register -> MFMA vs W2T -> gelu -> per-chunk sum/max
__global__ __launch_bounds__(256, 2) void k1_fused(
    const float* __restrict__ x,
    const float* __restrict__ W1,
    const float* __restrict__ b1,
    const unsigned short* __restrict__ w2t,
    const float* __restrict__ b2,
    float* __restrict__ psum,
    float* __restrict__ pmaxf)
{
    __shared__ char  sW[32768];       // W2T bf16, XOR-swizzled
    __shared__ float sW1[256];
    __shared__ float sb1[128];
    __shared__ float scrS[4][128];
    __shared__ float scrM[4][128];

    const int tid  = threadIdx.x;
    const int b    = blockIdx.x >> 5;
    const int c    = blockIdx.x & 31;
    const int lane = tid & 63;
    const int w    = tid >> 6;
    const int lr   = lane & 15;
    const int lk   = lane >> 4;
    const int swz  = (lr & 7) << 4;

    // stage W2T into LDS, swizzled: byte lb -> lb ^ ((row&7)<<4), row = lb>>8
    {
        const float4* src = (const float4*)w2t;  // 2048 x 16B
        #pragma unroll
        for (int it = 0; it < 8; ++it) {
            int cch = tid + it * 256;
            int dst = (cch << 4) ^ (((cch >> 4) & 7) << 4);
            *(float4*)(sW + dst) = src[cch];
        }
    }
    if (tid < 128) {
        sW1[tid]       = W1[tid];
        sW1[128 + tid] = W1[128 + tid];
        sb1[tid]       = b1[tid];
    }
    __syncthreads();

    // per-lane first-layer weights: features f = kt*32 + lk*8 + j
    __half2 wh[32];   // (w10, w11) pairs, f16
    float   b1r[32];
    #pragma unroll
    for (int kt = 0; kt < 4; ++kt) {
        #pragma unroll
        for (int j = 0; j < 8; ++j) {
            int f = kt * 32 + lk * 8 + j;
            wh[kt * 8 + j]  = __floats2half2_rn(sW1[f], sW1[128 + f]);
            b1r[kt * 8 + j] = sb1[f];
        }
    }
    float b2r[8];
    #pragma unroll
    for (int nt = 0; nt < 8; ++nt) b2r[nt] = b2[nt * 16 + lr];

    float runS[8], runM[8];
    #pragma unroll
    for (int nt = 0; nt < 8; ++nt) { runS[nt] = 0.0f; runM[nt] = -3.0e38f; }

    const float2* xr  = (const float2*)x + (size_t)b * L_LEN;
    const int     tk0 = c * CHUNK + w * 128;

    for (int it = 0; it < 4; ++it) {
        // ---- in-register h1 = gelu(dx@W1+b1), packed straight into A-fragments ----
        bf16x8 aF[2][4];
        #pragma unroll
        for (int rb = 0; rb < 2; ++rb) {
            int g = tk0 + it * 32 + rb * 16 + lr;
            float2 a0 = xr[g];
            int gn = g + 1; if (gn == L_LEN) gn = 0;   // circular roll
            float2 a1 = xr[gn];
            float dx0 = a1.x - a0.x, dx1 = a1.y - a0.y;
            #pragma unroll
            for (int kt = 0; kt < 4; ++kt) {
                unsigned pk[4];
                #pragma unroll
                for (int jp = 0; jp < 4; ++jp) {
                    __half2 w0 = wh[kt * 8 + 2 * jp];
                    __half2 w1 = wh[kt * 8 + 2 * jp + 1];
                    float p0 = fmaf(dx0, __low2float(w0), fmaf(dx1, __high2float(w0), b1r[kt * 8 + 2 * jp]));
                    float p1 = fmaf(dx0, __low2float(w1), fmaf(dx1, __high2float(w1), b1r[kt * 8 + 2 * jp + 1]));
                    pk[jp] = rhu_lo(gelu_f(p0)) | rhu_hi(gelu_f(p1));
                }
                union { u32x4 u; bf16x8 h; } cv;
                cv.u = (u32x4){pk[0], pk[1], pk[2], pk[3]};
                aF[rb][kt] = cv.h;
            }
        }

        // ---- MFMA: 32 tokens x 128 features, K=128 ----
        f32x4 acc[2][8];
        #pragma unroll
        for (int rb = 0; rb < 2; ++rb)
            #pragma unroll
            for (int nt = 0; nt < 8; ++nt)
                acc[rb][nt] = (f32x4){0.f, 0.f, 0.f, 0.f};

        #pragma unroll
        for (int kt = 0; kt < 4; ++kt) {
            #pragma unroll
            for (int nt = 0; nt < 8; ++nt) {
                int bo = ((nt * 16 + lr) << 8) + kt * 64 + (lk << 4);
                bo ^= swz;
                bf16x8 bF = *(const bf16x8*)(sW + bo);
                acc[0][nt] = __builtin_amdgcn_mfma_f32_16x16x32_bf16(aF[0][kt], bF, acc[0][nt], 0, 0, 0);
                acc[1][nt] = __builtin_amdgcn_mfma_f32_16x16x32_bf16(aF[1][kt], bF, acc[1][nt], 0, 0, 0);
            }
        }

        // ---- epilogue: +b2, gelu, per-feature sum/max over the 32 tokens ----
        #pragma unroll
        for (int nt = 0; nt < 8; ++nt) {
            float s = 0.0f, m = -3.0e38f;
            #pragma unroll
            for (int rb = 0; rb < 2; ++rb) {
                #pragma unroll
                for (int r = 0; r < 4; ++r) {
                    float v = gelu_f(acc[rb][nt][r] + b2r[nt]);
                    s += v;
                    m = fmaxf(m, v);
                }
            }
            s += __shfl_xor(s, 16, 64);
            s += __shfl_xor(s, 32, 64);
            m = fmaxf(m, __shfl_xor(m, 16, 64));
            m = fmaxf(m, __shfl_xor(m, 32, 64));
            runS[nt] += s;
            runM[nt] = fmaxf(runM[nt], m);
        }
    }

    // ---- cross-wave combine ----
    if (lk == 0) {
        #pragma unroll
        for (int nt = 0; nt < 8; ++nt) {
            scrS[w][nt * 16 + lr] = runS[nt];
            scrM[w][nt * 16 + lr] = runM[nt];
        }
    }
    __syncthreads();
    if (tid < 128) {
        float s = (scrS[0][tid] + scrS[1][tid]) + (scrS[2][tid] + scrS[3][tid]);
        float m = fmaxf(fmaxf(scrM[0][tid], scrM[1][tid]), fmaxf(scrM[2][tid], scrM[3][tid]));
        int o = (b * NCHUNK + c) * 128 + tid;
        psum[o]  = s;
        pmaxf[o] = m;
    }
}

// K2: reduce chunks -> mean/max -> z = cat@Wh + bh -> LayerNorm -> out
__global__ __launch_bounds__(128) void k2_final(
    const float* __restrict__ psum,
    const float* __restrict__ pmaxf,
    const float* __restrict__ Wh,
    const float* __restrict__ bh,
    const float* __restrict__ gamma,
    const float* __restrict__ beta,
    float* __restrict__ out)
{
    __shared__ float cat[256];
    __shared__ float red[4];
    const int b = blockIdx.x, f = threadIdx.x;
    float s = 0.0f, m = -3.0e38f;
    #pragma unroll
    for (int c = 0; c < NCHUNK; ++c) {
        int o = (b * NCHUNK + c) * 128 + f;
        s += psum[o];
        m = fmaxf(m, pmaxf[o]);
    }
    cat[f]       = s * (1.0f / 16384.0f);
    cat[128 + f] = m;
    __syncthreads();

    float z = bh[f];
    #pragma unroll 4
    for (int j = 0; j < 256; ++j) z = fmaf(cat[j], Wh[j * 128 + f], z);

    float s1 = z, s2 = z * z;
    #pragma unroll
    for (int off = 32; off >= 1; off >>= 1) {
        s1 += __shfl_xor(s1, off, 64);
        s2 += __shfl_xor(s2, off, 64);
    }
    int lane = f & 63, wv = f >> 6;
    if (lane == 0) { red[wv] = s1; red[2 + wv] = s2; }
    __syncthreads();
    float S1 = red[0] + red[1], S2 = red[2] + red[3];
    float mu  = S1 * (1.0f / 128.0f);
    float var = S2 * (1.0f / 128.0f) - mu * mu;
    out[b * 128 + f] = (z - mu) * rsqrtf(var + 1e-5f) * gamma[f] + beta[f];
}

extern "C" void kernel_launch(void* const* d_in, const int* in_sizes, int n_in,
                              void* d_out, int out_size, void* d_ws, size_t ws_size,
                              hipStream_t stream) {
    const float* x     = (const float*)d_in[0];
    const float* W1    = (const float*)d_in[1];
    const float* b1    = (const float*)d_in[2];
    const float* W2    = (const float*)d_in[3];
    const float* b2    = (const float*)d_in[4];
    const float* Wh    = (const float*)d_in[5];
    const float* bh    = (const float*)d_in[6];
    const float* gamma = (const float*)d_in[7];
    const float* beta  = (const float*)d_in[8];
    float* out = (float*)d_out;

    char* wsb = (char*)d_ws;
    unsigned short* w2t = (unsigned short*)wsb;                         // 32 KiB
    float* psum  = (float*)(wsb + 32768);                               // 1 MiB
    float* pmaxf = (float*)(wsb + 32768 + NB * NCHUNK * 128 * 4);       // 1 MiB

    k0_prep<<<64, 256, 0, stream>>>(W2, w2t);
    k1_fused<<<NB * NCHUNK, 256, 0, stream>>>(x, W1, b1, w2t, b2, psum, pmaxf);
    k2_final<<<NB, 128, 0, stream>>>(psum, pmaxf, Wh, bh, gamma, beta, out);
}

// Round 3
// 177.693 us; speedup vs baseline: 1.8063x; 1.8063x over previous
//
#include <hip/hip_runtime.h>
#include <hip/hip_bf16.h>
#include <hip/hip_fp16.h>

#define L_LEN 16384
#define NB 64
#define NCHUNK 32
#define CHUNK 512

typedef short bf16x8 __attribute__((ext_vector_type(8)));
typedef float f32x4 __attribute__((ext_vector_type(4)));
typedef unsigned int u32x4 __attribute__((ext_vector_type(4)));

__device__ __forceinline__ unsigned short f2bf(float f) {
    unsigned u = __float_as_uint(f);
    return (unsigned short)((u + 0x7FFFu + ((u >> 16) & 1u)) >> 16);  // RNE
}

// round-half-up float->bf16 (bits)
__device__ __forceinline__ unsigned rhu_lo(float f) {
    return (__float_as_uint(f) + 0x8000u) >> 16;
}
__device__ __forceinline__ unsigned rhu_hi(float f) {
    return (__float_as_uint(f) + 0x8000u) & 0xFFFF0000u;
}

// tanh-form GELU via sigmoid: x / (1 + exp2(x*(c1 + c2*x^2)))
__device__ __forceinline__ float gelu_f(float x) {
    float x2 = x * x;
    float f  = x * fmaf(-0.1029437f, x2, -2.30220789f);
    float e  = __builtin_amdgcn_exp2f(f);
    return x * __builtin_amdgcn_rcpf(1.0f + e);
}

// K0: W2 [128][128] f32 -> W2T [n][k] bf16 (transposed) in ws
__global__ __launch_bounds__(256) void k0_prep(const float* __restrict__ W2,
                                               unsigned short* __restrict__ w2t) {
    int i = blockIdx.x * 256 + threadIdx.x;   // 0..16383
    int n = i >> 7, k = i & 127;
    w2t[i] = f2bf(W2[k * 128 + n]);
}

// K1: fused dx -> gelu(dx@W1+b1) in-register -> MFMA vs W2T -> gelu -> per-chunk sum/max
__global__ __launch_bounds__(256) void k1_fused(
    const float* __restrict__ x,
    const float* __restrict__ W1,
    const float* __restrict__ b1,
    const unsigned short* __restrict__ w2t,
    const float* __restrict__ b2,
    float* __restrict__ psum,
    float* __restrict__ pmaxf)
{
    __shared__ char  sW[32768];       // W2T bf16, XOR-swizzled
    __shared__ float sW1[256];
    __shared__ float sb1[128];
    __shared__ float scrS[4][128];
    __shared__ float scrM[4][128];

    const int tid  = threadIdx.x;
    const int b    = blockIdx.x >> 5;
    const int c    = blockIdx.x & 31;
    const int lane = tid & 63;
    const int w    = tid >> 6;
    const int lr   = lane & 15;
    const int lk   = lane >> 4;
    const int swz  = (lr & 7) << 4;

    // stage W2T into LDS, swizzled: byte lb -> lb ^ ((row&7)<<4), row = lb>>8
    {
        const float4* src = (const float4*)w2t;  // 2048 x 16B
        #pragma unroll
        for (int it = 0; it < 8; ++it) {
            int cch = tid + it * 256;
            int dst = (cch << 4) ^ (((cch >> 4) & 7) << 4);
            *(float4*)(sW + dst) = src[cch];
        }
    }
    if (tid < 128) {
        sW1[tid]       = W1[tid];
        sW1[128 + tid] = W1[128 + tid];
        sb1[tid]       = b1[tid];
    }
    __syncthreads();

    // per-lane first-layer weights: features f = kt*32 + lk*8 + j
    __half2 wh[32];   // (w10, w11) pairs, f16
    __half2 b1h[16];  // b1 pairs, f16
    #pragma unroll
    for (int kt = 0; kt < 4; ++kt) {
        #pragma unroll
        for (int j = 0; j < 8; ++j) {
            int f = kt * 32 + lk * 8 + j;
            wh[kt * 8 + j] = __floats2half2_rn(sW1[f], sW1[128 + f]);
        }
        #pragma unroll
        for (int jp = 0; jp < 4; ++jp) {
            int f = kt * 32 + lk * 8 + 2 * jp;
            b1h[kt * 4 + jp] = __floats2half2_rn(sb1[f], sb1[f + 1]);
        }
    }
    float b2r[8];
    #pragma unroll
    for (int nt = 0; nt < 8; ++nt) b2r[nt] = b2[nt * 16 + lr];

    float runS[8], runM[8];
    #pragma unroll
    for (int nt = 0; nt < 8; ++nt) { runS[nt] = 0.0f; runM[nt] = -3.0e38f; }

    const float2* xr  = (const float2*)x + (size_t)b * L_LEN;
    const int     tk0 = c * CHUNK + w * 128;

    for (int it = 0; it < 4; ++it) {
        #pragma unroll
        for (int rb = 0; rb < 2; ++rb) {
            // ---- in-register h1 = gelu(dx@W1+b1) -> A-fragments for 16 tokens ----
            bf16x8 aF[4];
            {
                int g = tk0 + it * 32 + rb * 16 + lr;
                float2 a0 = xr[g];
                int gn = g + 1; if (gn == L_LEN) gn = 0;   // circular roll
                float2 a1 = xr[gn];
                float dx0 = a1.x - a0.x, dx1 = a1.y - a0.y;
                #pragma unroll
                for (int kt = 0; kt < 4; ++kt) {
                    unsigned pk[4];
                    #pragma unroll
                    for (int jp = 0; jp < 4; ++jp) {
                        __half2 w0 = wh[kt * 8 + 2 * jp];
                        __half2 w1 = wh[kt * 8 + 2 * jp + 1];
                        __half2 bb = b1h[kt * 4 + jp];
                        float p0 = fmaf(dx0, __low2float(w0), fmaf(dx1, __high2float(w0), __low2float(bb)));
                        float p1 = fmaf(dx0, __low2float(w1), fmaf(dx1, __high2float(w1), __high2float(bb)));
                        pk[jp] = rhu_lo(gelu_f(p0)) | rhu_hi(gelu_f(p1));
                    }
                    union { u32x4 u; bf16x8 h; } cv;
                    cv.u = (u32x4){pk[0], pk[1], pk[2], pk[3]};
                    aF[kt] = cv.h;
                }
            }

            // ---- MFMA: 16 tokens x 128 features, K=128 ----
            f32x4 acc[8];
            #pragma unroll
            for (int nt = 0; nt < 8; ++nt) acc[nt] = (f32x4){0.f, 0.f, 0.f, 0.f};

            #pragma unroll
            for (int kt = 0; kt < 4; ++kt) {
                #pragma unroll
                for (int nt = 0; nt < 8; ++nt) {
                    int bo = ((nt * 16 + lr) << 8) + kt * 64 + (lk << 4);
                    bo ^= swz;
                    bf16x8 bF = *(const bf16x8*)(sW + bo);
                    acc[nt] = __builtin_amdgcn_mfma_f32_16x16x32_bf16(aF[kt], bF, acc[nt], 0, 0, 0);
                }
            }

            // ---- epilogue: +b2, gelu, per-feature sum/max over the 16 tokens ----
            #pragma unroll
            for (int nt = 0; nt < 8; ++nt) {
                float s = 0.0f, m = -3.0e38f;
                #pragma unroll
                for (int r = 0; r < 4; ++r) {
                    float v = gelu_f(acc[nt][r] + b2r[nt]);
                    s += v;
                    m = fmaxf(m, v);
                }
                s += __shfl_xor(s, 16, 64);
                s += __shfl_xor(s, 32, 64);
                m = fmaxf(m, __shfl_xor(m, 16, 64));
                m = fmaxf(m, __shfl_xor(m, 32, 64));
                runS[nt] += s;
                runM[nt] = fmaxf(runM[nt], m);
            }
        }
    }

    // ---- cross-wave combine ----
    if (lk == 0) {
        #pragma unroll
        for (int nt = 0; nt < 8; ++nt) {
            scrS[w][nt * 16 + lr] = runS[nt];
            scrM[w][nt * 16 + lr] = runM[nt];
        }
    }
    __syncthreads();
    if (tid < 128) {
        float s = (scrS[0][tid] + scrS[1][tid]) + (scrS[2][tid] + scrS[3][tid]);
        float m = fmaxf(fmaxf(scrM[0][tid], scrM[1][tid]), fmaxf(scrM[2][tid], scrM[3][tid]));
        int o = (b * NCHUNK + c) * 128 + tid;
        psum[o]  = s;
        pmaxf[o] = m;
    }
}

// K2: reduce chunks -> mean/max -> z = cat@Wh + bh -> LayerNorm -> out
__global__ __launch_bounds__(128) void k2_final(
    const float* __restrict__ psum,
    const float* __restrict__ pmaxf,
    const float* __restrict__ Wh,
    const float* __restrict__ bh,
    const float* __restrict__ gamma,
    const float* __restrict__ beta,
    float* __restrict__ out)
{
    __shared__ float cat[256];
    __shared__ float red[4];
    const int b = blockIdx.x, f = threadIdx.x;
    float s = 0.0f, m = -3.0e38f;
    #pragma unroll
    for (int c = 0; c < NCHUNK; ++c) {
        int o = (b * NCHUNK + c) * 128 + f;
        s += psum[o];
        m = fmaxf(m, pmaxf[o]);
    }
    cat[f]       = s * (1.0f / 16384.0f);
    cat[128 + f] = m;
    __syncthreads();

    float z = bh[f];
    #pragma unroll 4
    for (int j = 0; j < 256; ++j) z = fmaf(cat[j], Wh[j * 128 + f], z);

    float s1 = z, s2 = z * z;
    #pragma unroll
    for (int off = 32; off >= 1; off >>= 1) {
        s1 += __shfl_xor(s1, off, 64);
        s2 += __shfl_xor(s2, off, 64);
    }
    int lane = f & 63, wv = f >> 6;
    if (lane == 0) { red[wv] = s1; red[2 + wv] = s2; }
    __syncthreads();
    float S1 = red[0] + red[1], S2 = red[2] + red[3];
    float mu  = S1 * (1.0f / 128.0f);
    float var = S2 * (1.0f / 128.0f) - mu * mu;
    out[b * 128 + f] = (z - mu) * rsqrtf(var + 1e-5f) * gamma[f] + beta[f];
}

extern "C" void kernel_launch(void* const* d_in, const int* in_sizes, int n_in,
                              void* d_out, int out_size, void* d_ws, size_t ws_size,
                              hipStream_t stream) {
    const float* x     = (const float*)d_in[0];
    const float* W1    = (const float*)d_in[1];
    const float* b1    = (const float*)d_in[2];
    const float* W2    = (const float*)d_in[3];
    const float* b2    = (const float*)d_in[4];
    const float* Wh    = (const float*)d_in[5];
    const float* bh    = (const float*)d_in[6];
    const float* gamma = (const float*)d_in[7];
    const float* beta  = (const float*)d_in[8];
    float* out = (float*)d_out;

    char* wsb = (char*)d_ws;
    unsigned short* w2t = (unsigned short*)wsb;                         // 32 KiB
    float* psum  = (float*)(wsb + 32768);                               // 1 MiB
    float* pmaxf = (float*)(wsb + 32768 + NB * NCHUNK * 128 * 4);       // 1 MiB

    k0_prep<<<64, 256, 0, stream>>>(W2, w2t);
    k1_fused<<<NB * NCHUNK, 256, 0, stream>>>(x, W1, b1, w2t, b2, psum, pmaxf);
    k2_final<<<NB, 128, 0, stream>>>(psum, pmaxf, Wh, bh, gamma, beta, out);
}

// Round 4
// 111.689 us; speedup vs baseline: 2.8737x; 1.5910x over previous
//
#include <hip/hip_runtime.h>
#include <hip/hip_bf16.h>
#include <hip/hip_fp16.h>

#define L_LEN 16384
#define NB 64
#define NCHUNK 32
#define CHUNK 512

typedef short bf16x8 __attribute__((ext_vector_type(8)));
typedef float f32x4 __attribute__((ext_vector_type(4)));
typedef unsigned int u32x4 __attribute__((ext_vector_type(4)));

__device__ __forceinline__ unsigned short f2bf(float f) {
    unsigned u = __float_as_uint(f);
    return (unsigned short)((u + 0x7FFFu + ((u >> 16) & 1u)) >> 16);  // RNE
}

// tanh-form GELU via sigmoid: x / (1 + exp2(x*(c1 + c2*x^2)))
__device__ __forceinline__ float gelu_f(float x) {
    float x2 = x * x;
    float f  = x * fmaf(-0.1029437f, x2, -2.30220789f);
    float e  = __builtin_amdgcn_exp2f(f);
    return x * __builtin_amdgcn_rcpf(1.0f + e);
}

// packed RNE f32x2 -> bf16x2 (single instruction on gfx950)
__device__ __forceinline__ unsigned cvt_pk_bf16(float lo, float hi) {
    unsigned r;
    asm("v_cvt_pk_bf16_f32 %0, %1, %2" : "=v"(r) : "v"(lo), "v"(hi));
    return r;
}

// K0: W2 [128][128] f32 -> W2T [n][k] bf16 (transposed) in ws
__global__ __launch_bounds__(256) void k0_prep(const float* __restrict__ W2,
                                               unsigned short* __restrict__ w2t) {
    int i = blockIdx.x * 256 + threadIdx.x;   // 0..16383
    int n = i >> 7, k = i & 127;
    w2t[i] = f2bf(W2[k * 128 + n]);
}

// K1: fused dx -> gelu(dx@W1+b1) in-register -> MFMA vs W2T -> gelu -> per-chunk sum/max
__global__ __launch_bounds__(256) void k1_fused(
    const float* __restrict__ x,
    const float* __restrict__ W1,
    const float* __restrict__ b1,
    const unsigned short* __restrict__ w2t,
    const float* __restrict__ b2,
    float* __restrict__ psum,
    float* __restrict__ pmaxf)
{
    __shared__ char  sW[32768];       // W2T bf16, XOR-swizzled
    __shared__ float sW1f[256];       // [2][128] f32
    __shared__ float sb1f[128];
    __shared__ float scrS[4][128];
    __shared__ float scrM[4][128];

    const int tid  = threadIdx.x;
    const int b    = blockIdx.x >> 5;
    const int c    = blockIdx.x & 31;
    const int lane = tid & 63;
    const int w    = tid >> 6;
    const int lr   = lane & 15;
    const int lk   = lane >> 4;
    const int swz  = (lr & 7) << 4;

    // stage W2T into LDS, swizzled: byte lb -> lb ^ ((row&7)<<4), row = lb>>8
    {
        const float4* src = (const float4*)w2t;  // 2048 x 16B
        #pragma unroll
        for (int it = 0; it < 8; ++it) {
            int cch = tid + it * 256;
            int dst = (cch << 4) ^ (((cch >> 4) & 7) << 4);
            *(float4*)(sW + dst) = src[cch];
        }
    }
    if (tid < 128) {
        sW1f[tid]       = W1[tid];
        sW1f[128 + tid] = W1[128 + tid];
        sb1f[tid]       = b1[tid];
    }
    __syncthreads();

    float b2r[8];
    #pragma unroll
    for (int nt = 0; nt < 8; ++nt) b2r[nt] = b2[nt * 16 + lr];

    float runS[8], runM[8];
    #pragma unroll
    for (int nt = 0; nt < 8; ++nt) { runS[nt] = 0.0f; runM[nt] = -3.0e38f; }

    const float2* xr  = (const float2*)x + (size_t)b * L_LEN;
    const int     tk0 = c * CHUNK + w * 128;

    const float* w0base = sW1f + lk * 8;
    const float* w1base = sW1f + 128 + lk * 8;
    const float* bbase  = sb1f + lk * 8;

    for (int it = 0; it < 4; ++it) {
        #pragma unroll
        for (int rb = 0; rb < 2; ++rb) {
            int g = tk0 + it * 32 + rb * 16 + lr;
            float2 a0 = xr[g];
            int gn = g + 1; if (gn == L_LEN) gn = 0;   // circular roll
            float2 a1 = xr[gn];
            float dx0 = a1.x - a0.x, dx1 = a1.y - a0.y;

            f32x4 acc[8];
            #pragma unroll
            for (int nt = 0; nt < 8; ++nt) acc[nt] = (f32x4){0.f, 0.f, 0.f, 0.f};

            #pragma unroll
            for (int kt = 0; kt < 4; ++kt) {
                // per-lane W1 slice from LDS (broadcast within lk group)
                float4 w0a = *(const float4*)(w0base + kt * 32);
                float4 w0b = *(const float4*)(w0base + kt * 32 + 4);
                float4 w1a = *(const float4*)(w1base + kt * 32);
                float4 w1b = *(const float4*)(w1base + kt * 32 + 4);
                float4 ba  = *(const float4*)(bbase  + kt * 32);
                float4 bb  = *(const float4*)(bbase  + kt * 32 + 4);

                float h[8];
                #pragma unroll
                for (int j = 0; j < 4; ++j)
                    h[j]     = gelu_f(fmaf(dx0, w0a[j], fmaf(dx1, w1a[j], ba[j])));
                #pragma unroll
                for (int j = 0; j < 4; ++j)
                    h[4 + j] = gelu_f(fmaf(dx0, w0b[j], fmaf(dx1, w1b[j], bb[j])));

                union { u32x4 u; bf16x8 v; } cv;
                cv.u = (u32x4){cvt_pk_bf16(h[0], h[1]), cvt_pk_bf16(h[2], h[3]),
                               cvt_pk_bf16(h[4], h[5]), cvt_pk_bf16(h[6], h[7])};
                bf16x8 aF = cv.v;

                #pragma unroll
                for (int nt = 0; nt < 8; ++nt) {
                    int bo = ((nt * 16 + lr) << 8) + kt * 64 + (lk << 4);
                    bo ^= swz;
                    bf16x8 bF = *(const bf16x8*)(sW + bo);
                    acc[nt] = __builtin_amdgcn_mfma_f32_16x16x32_bf16(aF, bF, acc[nt], 0, 0, 0);
                }
            }

            // epilogue: +b2, gelu, local (4-token) sum/max only — lk-reduce deferred
            #pragma unroll
            for (int nt = 0; nt < 8; ++nt) {
                float s = 0.0f, m = -3.0e38f;
                #pragma unroll
                for (int r = 0; r < 4; ++r) {
                    float v = gelu_f(acc[nt][r] + b2r[nt]);
                    s += v;
                    m = fmaxf(m, v);
                }
                runS[nt] += s;
                runM[nt] = fmaxf(runM[nt], m);
            }
        }
    }

    // deferred cross-lk reduction (once)
    #pragma unroll
    for (int nt = 0; nt < 8; ++nt) {
        float s = runS[nt];
        s += __shfl_xor(s, 16, 64);
        s += __shfl_xor(s, 32, 64);
        float m = runM[nt];
        m = fmaxf(m, __shfl_xor(m, 16, 64));
        m = fmaxf(m, __shfl_xor(m, 32, 64));
        runS[nt] = s;
        runM[nt] = m;
    }

    // cross-wave combine
    if (lk == 0) {
        #pragma unroll
        for (int nt = 0; nt < 8; ++nt) {
            scrS[w][nt * 16 + lr] = runS[nt];
            scrM[w][nt * 16 + lr] = runM[nt];
        }
    }
    __syncthreads();
    if (tid < 128) {
        float s = (scrS[0][tid] + scrS[1][tid]) + (scrS[2][tid] + scrS[3][tid]);
        float m = fmaxf(fmaxf(scrM[0][tid], scrM[1][tid]), fmaxf(scrM[2][tid], scrM[3][tid]));
        int o = (b * NCHUNK + c) * 128 + tid;
        psum[o]  = s;
        pmaxf[o] = m;
    }
}

// K2: reduce chunks -> mean/max -> z = cat@Wh + bh -> LayerNorm -> out
__global__ __launch_bounds__(128) void k2_final(
    const float* __restrict__ psum,
    const float* __restrict__ pmaxf,
    const float* __restrict__ Wh,
    const float* __restrict__ bh,
    const float* __restrict__ gamma,
    const float* __restrict__ beta,
    float* __restrict__ out)
{
    __shared__ float cat[256];
    __shared__ float red[4];
    const int b = blockIdx.x, f = threadIdx.x;
    float s = 0.0f, m = -3.0e38f;
    #pragma unroll
    for (int c = 0; c < NCHUNK; ++c) {
        int o = (b * NCHUNK + c) * 128 + f;
        s += psum[o];
        m = fmaxf(m, pmaxf[o]);
    }
    cat[f]       = s * (1.0f / 16384.0f);
    cat[128 + f] = m;
    __syncthreads();

    float z = bh[f];
    #pragma unroll 4
    for (int j = 0; j < 256; ++j) z = fmaf(cat[j], Wh[j * 128 + f], z);

    float s1 = z, s2 = z * z;
    #pragma unroll
    for (int off = 32; off >= 1; off >>= 1) {
        s1 += __shfl_xor(s1, off, 64);
        s2 += __shfl_xor(s2, off, 64);
    }
    int lane = f & 63, wv = f >> 6;
    if (lane == 0) { red[wv] = s1; red[2 + wv] = s2; }
    __syncthreads();
    float S1 = red[0] + red[1], S2 = red[2] + red[3];
    float mu  = S1 * (1.0f / 128.0f);
    float var = S2 * (1.0f / 128.0f) - mu * mu;
    out[b * 128 + f] = (z - mu) * rsqrtf(var + 1e-5f) * gamma[f] + beta[f];
}

extern "C" void kernel_launch(void* const* d_in, const int* in_sizes, int n_in,
                              void* d_out, int out_size, void* d_ws, size_t ws_size,
                              hipStream_t stream) {
    const float* x     = (const float*)d_in[0];
    const float* W1    = (const float*)d_in[1];
    const float* b1    = (const float*)d_in[2];
    const float* W2    = (const float*)d_in[3];
    const float* b2    = (const float*)d_in[4];
    const float* Wh    = (const float*)d_in[5];
    const float* bh    = (const float*)d_in[6];
    const float* gamma = (const float*)d_in[7];
    const float* beta  = (const float*)d_in[8];
    float* out = (float*)d_out;

    char* wsb = (char*)d_ws;
    unsigned short* w2t = (unsigned short*)wsb;                         // 32 KiB
    float* psum  = (float*)(wsb + 32768);                               // 1 MiB
    float* pmaxf = (float*)(wsb + 32768 + NB * NCHUNK * 128 * 4);       // 1 MiB

    k0_prep<<<64, 256, 0, stream>>>(W2, w2t);
    k1_fused<<<NB * NCHUNK, 256, 0, stream>>>(x, W1, b1, w2t, b2, psum, pmaxf);
    k2_final<<<NB, 128, 0, stream>>>(psum, pmaxf, Wh, bh, gamma, beta, out);
}

// Round 5
// 107.216 us; speedup vs baseline: 2.9936x; 1.0417x over previous
//
#include <hip/hip_runtime.h>
#include <hip/hip_bf16.h>
#include <hip/hip_fp16.h>

#define L_LEN 16384
#define NB 64
#define NCHUNK 32
#define CHUNK 512

typedef short bf16x8 __attribute__((ext_vector_type(8)));
typedef float f32x4 __attribute__((ext_vector_type(4)));
typedef unsigned int u32x4 __attribute__((ext_vector_type(4)));

__device__ __forceinline__ unsigned short f2bf(float f) {
    unsigned u = __float_as_uint(f);
    return (unsigned short)((u + 0x7FFFu + ((u >> 16) & 1u)) >> 16);  // RNE
}

// packed RNE f32x2 -> bf16x2 (single instruction on gfx950)
__device__ __forceinline__ unsigned cvt_pk_bf16(float lo, float hi) {
    unsigned r;
    asm("v_cvt_pk_bf16_f32 %0, %1, %2" : "=v"(r) : "v"(lo), "v"(hi));
    return r;
}

// K0: blocks 0..63: W2 [128][128] f32 -> W2T [n][k] bf16 (transposed).
//     block 64: build 512-entry piecewise-linear GELU table over [-8,8), step 1/32.
//     Entry i: s = (g(x_{i+1})-g(x_i))*32 ; v' = g(x_i) - s*x_i  =>  g(p) ~= fma(s, p, v').
//     Slope->1 (x>8) and ->0 (x<-8) make extrapolation exact for clamped indices.
__global__ __launch_bounds__(256) void k0_prep(const float* __restrict__ W2,
                                               unsigned short* __restrict__ w2t,
                                               float2* __restrict__ gtab) {
    if (blockIdx.x < 64) {
        int i = blockIdx.x * 256 + threadIdx.x;   // 0..16383
        int n = i >> 7, k = i & 127;
        w2t[i] = f2bf(W2[k * 128 + n]);
    } else {
        for (int e = threadIdx.x; e < 512; e += 256) {
            double x0 = (double)e * (1.0 / 32.0) - 8.0;
            double x1 = x0 + (1.0 / 32.0);
            double g0 = 0.5 * x0 * (1.0 + erf(x0 * 0.7071067811865476));
            double g1 = 0.5 * x1 * (1.0 + erf(x1 * 0.7071067811865476));
            double s  = (g1 - g0) * 32.0;
            double v  = g0 - s * x0;
            gtab[e] = make_float2((float)v, (float)s);
        }
    }
}

// K1: fused dx -> gelu(dx@W1+b1) in-register -> MFMA vs W2T -> gelu -> per-chunk sum/max
__global__ __launch_bounds__(256) void k1_fused(
    const float* __restrict__ x,
    const float* __restrict__ W1,
    const float* __restrict__ b1,
    const unsigned short* __restrict__ w2t,
    const float2* __restrict__ gtab,
    const float* __restrict__ b2,
    float* __restrict__ psum,
    float* __restrict__ pmaxf)
{
    __shared__ char   sW[32768];      // W2T bf16, XOR-swizzled (scratch overlaid at end)
    __shared__ float2 sTab[512];      // GELU LUT
    __shared__ float  sW1f[256];      // [2][128] f32
    __shared__ float  sb1f[128];

    const int tid  = threadIdx.x;
    const int b    = blockIdx.x >> 5;
    const int c    = blockIdx.x & 31;
    const int lane = tid & 63;
    const int w    = tid >> 6;
    const int lr   = lane & 15;
    const int lk   = lane >> 4;
    const int swz  = (lr & 7) << 4;

    // stage W2T into LDS, swizzled: byte lb -> lb ^ ((row&7)<<4), row = lb>>8
    {
        const float4* src = (const float4*)w2t;  // 2048 x 16B
        #pragma unroll
        for (int it = 0; it < 8; ++it) {
            int cch = tid + it * 256;
            int dst = (cch << 4) ^ (((cch >> 4) & 7) << 4);
            *(float4*)(sW + dst) = src[cch];
        }
    }
    {   // GELU table: 256 threads x 16B = 4 KiB
        float4 v = ((const float4*)gtab)[tid];
        *(float4*)&sTab[tid * 2] = v;
    }
    if (tid < 128) {
        sW1f[tid]       = W1[tid];
        sW1f[128 + tid] = W1[128 + tid];
        sb1f[tid]       = b1[tid];
    }
    __syncthreads();

    float b2r[8];
    #pragma unroll
    for (int nt = 0; nt < 8; ++nt) b2r[nt] = b2[nt * 16 + lr];

    float runS[8], runM[8];
    #pragma unroll
    for (int nt = 0; nt < 8; ++nt) { runS[nt] = 0.0f; runM[nt] = -3.0e38f; }

    const float2* xr  = (const float2*)x + (size_t)b * L_LEN;
    const int     tk0 = c * CHUNK + w * 128;

    const float* w0base = sW1f + lk * 8;
    const float* w1base = sW1f + 128 + lk * 8;
    const float* bbase  = sb1f + lk * 8;

    // LUT gelu: g(p) = fma(s[i], p, v'[i]), i = clamp-index; extrapolation exact at both ends
    #define GELU_LUT(p, out) {                                          \
        float xm_ = __builtin_amdgcn_fmed3f((p), -8.0f, 7.96875f);      \
        float t_  = fmaf(xm_, 32.0f, 256.0f);                           \
        int   i_  = (int)t_;                                            \
        float2 vs_ = sTab[i_];                                          \
        (out) = fmaf(vs_.y, (p), vs_.x);                                \
    }

    for (int it = 0; it < 4; ++it) {
        #pragma unroll
        for (int rb = 0; rb < 2; ++rb) {
            int g = tk0 + it * 32 + rb * 16 + lr;
            float2 a0 = xr[g];
            int gn = g + 1; if (gn == L_LEN) gn = 0;   // circular roll
            float2 a1 = xr[gn];
            float dx0 = a1.x - a0.x, dx1 = a1.y - a0.y;

            f32x4 acc[8];
            #pragma unroll
            for (int nt = 0; nt < 8; ++nt) acc[nt] = (f32x4){0.f, 0.f, 0.f, 0.f};

            #pragma unroll
            for (int kt = 0; kt < 4; ++kt) {
                // per-lane W1 slice from LDS (broadcast within lk group)
                float4 w0a = *(const float4*)(w0base + kt * 32);
                float4 w0b = *(const float4*)(w0base + kt * 32 + 4);
                float4 w1a = *(const float4*)(w1base + kt * 32);
                float4 w1b = *(const float4*)(w1base + kt * 32 + 4);
                float4 ba  = *(const float4*)(bbase  + kt * 32);
                float4 bb  = *(const float4*)(bbase  + kt * 32 + 4);

                float h[8];
                #pragma unroll
                for (int j = 0; j < 4; ++j) {
                    float p = fmaf(dx0, w0a[j], fmaf(dx1, w1a[j], ba[j]));
                    GELU_LUT(p, h[j]);
                }
                #pragma unroll
                for (int j = 0; j < 4; ++j) {
                    float p = fmaf(dx0, w0b[j], fmaf(dx1, w1b[j], bb[j]));
                    GELU_LUT(p, h[4 + j]);
                }

                union { u32x4 u; bf16x8 v; } cv;
                cv.u = (u32x4){cvt_pk_bf16(h[0], h[1]), cvt_pk_bf16(h[2], h[3]),
                               cvt_pk_bf16(h[4], h[5]), cvt_pk_bf16(h[6], h[7])};
                bf16x8 aF = cv.v;

                #pragma unroll
                for (int nt = 0; nt < 8; ++nt) {
                    int bo = ((nt * 16 + lr) << 8) + kt * 64 + (lk << 4);
                    bo ^= swz;
                    bf16x8 bF = *(const bf16x8*)(sW + bo);
                    acc[nt] = __builtin_amdgcn_mfma_f32_16x16x32_bf16(aF, bF, acc[nt], 0, 0, 0);
                }
            }

            // epilogue: +b2, gelu, local (4-token) sum/max only — lk-reduce deferred
            #pragma unroll
            for (int nt = 0; nt < 8; ++nt) {
                float s = 0.0f, m = -3.0e38f;
                #pragma unroll
                for (int r = 0; r < 4; ++r) {
                    float p = acc[nt][r] + b2r[nt];
                    float v;
                    GELU_LUT(p, v);
                    s += v;
                    m = fmaxf(m, v);
                }
                runS[nt] += s;
                runM[nt] = fmaxf(runM[nt], m);
            }
        }
    }

    // deferred cross-lk reduction (once)
    #pragma unroll
    for (int nt = 0; nt < 8; ++nt) {
        float s = runS[nt];
        s += __shfl_xor(s, 16, 64);
        s += __shfl_xor(s, 32, 64);
        float m = runM[nt];
        m = fmaxf(m, __shfl_xor(m, 16, 64));
        m = fmaxf(m, __shfl_xor(m, 32, 64));
        runS[nt] = s;
        runM[nt] = m;
    }

    // cross-wave combine — scratch overlays sW (all MFMA reads done; barrier first)
    __syncthreads();
    float* scrS = (float*)sW;            // [4][128]
    float* scrM = (float*)(sW + 2048);   // [4][128]
    if (lk == 0) {
        #pragma unroll
        for (int nt = 0; nt < 8; ++nt) {
            scrS[w * 128 + nt * 16 + lr] = runS[nt];
            scrM[w * 128 + nt * 16 + lr] = runM[nt];
        }
    }
    __syncthreads();
    if (tid < 128) {
        float s = (scrS[tid] + scrS[128 + tid]) + (scrS[256 + tid] + scrS[384 + tid]);
        float m = fmaxf(fmaxf(scrM[tid], scrM[128 + tid]), fmaxf(scrM[256 + tid], scrM[384 + tid]));
        int o = (b * NCHUNK + c) * 128 + tid;
        psum[o]  = s;
        pmaxf[o] = m;
    }
}

// K2: reduce chunks -> mean/max -> z = cat@Wh + bh -> LayerNorm -> out
__global__ __launch_bounds__(128) void k2_final(
    const float* __restrict__ psum,
    const float* __restrict__ pmaxf,
    const float* __restrict__ Wh,
    const float* __restrict__ bh,
    const float* __restrict__ gamma,
    const float* __restrict__ beta,
    float* __restrict__ out)
{
    __shared__ float cat[256];
    __shared__ float red[4];
    const int b = blockIdx.x, f = threadIdx.x;
    float s = 0.0f, m = -3.0e38f;
    #pragma unroll
    for (int c = 0; c < NCHUNK; ++c) {
        int o = (b * NCHUNK + c) * 128 + f;
        s += psum[o];
        m = fmaxf(m, pmaxf[o]);
    }
    cat[f]       = s * (1.0f / 16384.0f);
    cat[128 + f] = m;
    __syncthreads();

    float z = bh[f];
    #pragma unroll 4
    for (int j = 0; j < 256; ++j) z = fmaf(cat[j], Wh[j * 128 + f], z);

    float s1 = z, s2 = z * z;
    #pragma unroll
    for (int off = 32; off >= 1; off >>= 1) {
        s1 += __shfl_xor(s1, off, 64);
        s2 += __shfl_xor(s2, off, 64);
    }
    int lane = f & 63, wv = f >> 6;
    if (lane == 0) { red[wv] = s1; red[2 + wv] = s2; }
    __syncthreads();
    float S1 = red[0] + red[1], S2 = red[2] + red[3];
    float mu  = S1 * (1.0f / 128.0f);
    float var = S2 * (1.0f / 128.0f) - mu * mu;
    out[b * 128 + f] = (z - mu) * rsqrtf(var + 1e-5f) * gamma[f] + beta[f];
}

extern "C" void kernel_launch(void* const* d_in, const int* in_sizes, int n_in,
                              void* d_out, int out_size, void* d_ws, size_t ws_size,
                              hipStream_t stream) {
    const float* x     = (const float*)d_in[0];
    const float* W1    = (const float*)d_in[1];
    const float* b1    = (const float*)d_in[2];
    const float* W2    = (const float*)d_in[3];
    const float* b2    = (const float*)d_in[4];
    const float* Wh    = (const float*)d_in[5];
    const float* bh    = (const float*)d_in[6];
    const float* gamma = (const float*)d_in[7];
    const float* beta  = (const float*)d_in[8];
    float* out = (float*)d_out;

    char* wsb = (char*)d_ws;
    unsigned short* w2t = (unsigned short*)wsb;                         // 32 KiB
    float2* gtab = (float2*)(wsb + 32768);                              // 4 KiB
    float* psum  = (float*)(wsb + 36864);                               // 1 MiB
    float* pmaxf = (float*)(wsb + 36864 + NB * NCHUNK * 128 * 4);       // 1 MiB

    k0_prep<<<65, 256, 0, stream>>>(W2, w2t, gtab);
    k1_fused<<<NB * NCHUNK, 256, 0, stream>>>(x, W1, b1, w2t, gtab, b2, psum, pmaxf);
    k2_final<<<NB, 128, 0, stream>>>(psum, pmaxf, Wh, bh, gamma, beta, out);
}